// Round 9
// baseline (57.399 us; speedup 1.0000x reference)
//
#include <hip/hip_runtime.h>

#define HH 1024
#define WW 1024
#define NR 16                          // output rows per block
#define STRIPS (HH / NR)               // 64 strips per image
#define NBLK (32 * STRIPS)             // 2048 blocks, 8192 waves
#define NXCD 8
#define PERX (NBLK / NXCD)             // 256 blocks per XCD

struct Row { float l; float4 v; float r; };

__device__ __forceinline__ Row ldrow(const float* __restrict__ img, int y,
                                     int x0, int xl, int xr) {
    const float* p = img + (size_t)y * WW;
    Row r;
    r.v = *reinterpret_cast<const float4*>(p + x0);
    r.l = p[xl];                        // clamped halo: neighbor's cache line
    r.r = p[xr];
    return r;
}

__global__ __launch_bounds__(256) void sobel_loss_kernel(
    const float* __restrict__ fake, const float* __restrict__ real,
    float* __restrict__ pnum, unsigned int* __restrict__ pcnt)
{
    const int t   = threadIdx.x;
    const int bid = blockIdx.x;
    // XCD-contiguous remap: dispatch round-robins blockIdx across the 8 XCDs;
    // give XCD x a CONTIGUOUS strip range so ±1 halo rows of adjacent strips
    // hit the same XCD's L2 instead of re-crossing the fabric.
    const int wid = (bid & (NXCD - 1)) * PERX + (bid >> 3);
    const int b   = wid / STRIPS;
    const int y0  = (wid % STRIPS) * NR;
    const float* fimg = fake + (size_t)b * HH * WW;
    const float* rimg = real + (size_t)b * HH * WW;

    const int x0 = 4 * t;
    const int xl = max(x0 - 1, 0);          // clamp -> edge replicate
    const int xr = min(x0 + 4, WW - 1);

    Row fp_ = ldrow(fimg, max(y0 - 1, 0), x0, xl, xr);
    Row fc_ = ldrow(fimg, y0,             x0, xl, xr);
    Row rp_ = ldrow(rimg, max(y0 - 1, 0), x0, xl, xr);
    Row rc_ = ldrow(rimg, y0,             x0, xl, xr);

    float num = 0.f;
    int   cnt = 0;

    #pragma unroll
    for (int i = 0; i < NR; ++i) {
        const int yn = min(y0 + i + 1, HH - 1);
        Row fn_ = ldrow(fimg, yn, x0, xl, xr);
        Row rn_ = ldrow(rimg, yn, x0, xl, xr);

        // vertical smooth S = (p + 2c) + n  — exact jax FP order
        const float fSm = fp_.l + 2.f * fc_.l + fn_.l;
        const float rSm = rp_.l + 2.f * rc_.l + rn_.l;
        float4 fS, rS;
        fS.x = fp_.v.x + 2.f * fc_.v.x + fn_.v.x;
        fS.y = fp_.v.y + 2.f * fc_.v.y + fn_.v.y;
        fS.z = fp_.v.z + 2.f * fc_.v.z + fn_.v.z;
        fS.w = fp_.v.w + 2.f * fc_.v.w + fn_.v.w;
        rS.x = rp_.v.x + 2.f * rc_.v.x + rn_.v.x;
        rS.y = rp_.v.y + 2.f * rc_.v.y + rn_.v.y;
        rS.z = rp_.v.z + 2.f * rc_.v.z + rn_.v.z;
        rS.w = rp_.v.w + 2.f * rc_.v.w + rn_.v.w;
        const float fSp = fp_.r + 2.f * fc_.r + fn_.r;
        const float rSp = rp_.r + 2.f * rc_.r + rn_.r;

        float ef, er;
        er = rS.y - rSm;  ef = fS.y - fSm;  if (er > 0.f) { num += fabsf(ef - er); ++cnt; }
        er = rS.z - rS.x; ef = fS.z - fS.x; if (er > 0.f) { num += fabsf(ef - er); ++cnt; }
        er = rS.w - rS.y; ef = fS.w - fS.y; if (er > 0.f) { num += fabsf(ef - er); ++cnt; }
        er = rSp - rS.z;  ef = fSp - fS.z;  if (er > 0.f) { num += fabsf(ef - er); ++cnt; }

        fp_ = fc_; fc_ = fn_;
        rp_ = rc_; rc_ = rn_;
    }

    // wave reduce -> block reduce -> ONE plain store per block (no atomics)
    for (int off = 32; off; off >>= 1) {
        num += __shfl_down(num, off);
        cnt += __shfl_down(cnt, off);
    }
    __shared__ float wnum[4];
    __shared__ int   wcnt[4];
    const int wave = t >> 6, lane = t & 63;
    if (lane == 0) { wnum[wave] = num; wcnt[wave] = cnt; }
    __syncthreads();
    if (t == 0) {
        pnum[bid] = wnum[0] + wnum[1] + wnum[2] + wnum[3];
        pcnt[bid] = (unsigned int)(wcnt[0] + wcnt[1] + wcnt[2] + wcnt[3]);
    }
}

__global__ __launch_bounds__(256) void reduce_kernel(
    const float* __restrict__ pnum, const unsigned int* __restrict__ pcnt,
    float* __restrict__ out)
{
    const int t = threadIdx.x;
    double             n = 0.0;
    unsigned long long c = 0;
    for (int i = t; i < NBLK; i += 256) { n += (double)pnum[i]; c += pcnt[i]; }
    for (int off = 32; off; off >>= 1) {
        n += __shfl_down(n, off);
        c += __shfl_down(c, off);
    }
    __shared__ double             sn[4];
    __shared__ unsigned long long sc[4];
    const int wave = t >> 6, lane = t & 63;
    if (lane == 0) { sn[wave] = n; sc[wave] = c; }
    __syncthreads();
    if (t == 0) {
        const double N = sn[0] + sn[1] + sn[2] + sn[3];
        const double C = (double)(sc[0] + sc[1] + sc[2] + sc[3]);
        out[0] = (float)(N / C / 32.0);
    }
}

extern "C" void kernel_launch(void* const* d_in, const int* in_sizes, int n_in,
                              void* d_out, int out_size, void* d_ws, size_t ws_size,
                              hipStream_t stream)
{
    const float* fake = (const float*)d_in[0];
    const float* real = (const float*)d_in[1];
    float* out = (float*)d_out;

    float*        pnum = (float*)d_ws;                            // 2048 floats
    unsigned int* pcnt = (unsigned int*)((char*)d_ws + NBLK * 4); // 2048 uints

    sobel_loss_kernel<<<NBLK, 256, 0, stream>>>(fake, real, pnum, pcnt);
    reduce_kernel<<<1, 256, 0, stream>>>(pnum, pcnt, out);
}

// Round 10
// 48.735 us; speedup vs baseline: 1.1778x; 1.1778x over previous
//
#include <hip/hip_runtime.h>

#define HH 1024
#define WW 1024
#define NR 32                          // output rows per block (halo = 2/32 = 6.25%)
#define STRIPS (HH / NR)               // 32 strips per image
#define NBLK (32 * STRIPS)             // 1024 blocks, 4096 waves

struct Row { float l; float4 v; float r; };

__device__ __forceinline__ Row ldrow(const float* __restrict__ img, int y,
                                     int x0, int xl, int xr) {
    const float* p = img + (size_t)y * WW;
    Row r;
    r.v = *reinterpret_cast<const float4*>(p + x0);
    r.l = p[xl];                        // clamped halo: neighbor's cache line
    r.r = p[xr];
    return r;
}

__global__ __launch_bounds__(256) void sobel_loss_kernel(
    const float* __restrict__ fake, const float* __restrict__ real,
    float* __restrict__ pnum, unsigned int* __restrict__ pcnt)
{
    const int t  = threadIdx.x;
    const int b  = blockIdx.x / STRIPS;
    const int y0 = (blockIdx.x % STRIPS) * NR;
    const float* fimg = fake + (size_t)b * HH * WW;
    const float* rimg = real + (size_t)b * HH * WW;

    const int x0 = 4 * t;
    const int xl = max(x0 - 1, 0);          // clamp -> edge replicate
    const int xr = min(x0 + 4, WW - 1);

    Row fp_ = ldrow(fimg, max(y0 - 1, 0), x0, xl, xr);
    Row fc_ = ldrow(fimg, y0,             x0, xl, xr);
    Row rp_ = ldrow(rimg, max(y0 - 1, 0), x0, xl, xr);
    Row rc_ = ldrow(rimg, y0,             x0, xl, xr);

    float num = 0.f;
    int   cnt = 0;

    #pragma unroll
    for (int i = 0; i < NR; ++i) {
        const int yn = min(y0 + i + 1, HH - 1);
        Row fn_ = ldrow(fimg, yn, x0, xl, xr);
        Row rn_ = ldrow(rimg, yn, x0, xl, xr);

        // vertical smooth S = (p + 2c) + n  — exact jax FP order
        const float fSm = fp_.l + 2.f * fc_.l + fn_.l;
        const float rSm = rp_.l + 2.f * rc_.l + rn_.l;
        float4 fS, rS;
        fS.x = fp_.v.x + 2.f * fc_.v.x + fn_.v.x;
        fS.y = fp_.v.y + 2.f * fc_.v.y + fn_.v.y;
        fS.z = fp_.v.z + 2.f * fc_.v.z + fn_.v.z;
        fS.w = fp_.v.w + 2.f * fc_.v.w + fn_.v.w;
        rS.x = rp_.v.x + 2.f * rc_.v.x + rn_.v.x;
        rS.y = rp_.v.y + 2.f * rc_.v.y + rn_.v.y;
        rS.z = rp_.v.z + 2.f * rc_.v.z + rn_.v.z;
        rS.w = rp_.v.w + 2.f * rc_.v.w + rn_.v.w;
        const float fSp = fp_.r + 2.f * fc_.r + fn_.r;
        const float rSp = rp_.r + 2.f * rc_.r + rn_.r;

        float ef, er;
        er = rS.y - rSm;  ef = fS.y - fSm;  if (er > 0.f) { num += fabsf(ef - er); ++cnt; }
        er = rS.z - rS.x; ef = fS.z - fS.x; if (er > 0.f) { num += fabsf(ef - er); ++cnt; }
        er = rS.w - rS.y; ef = fS.w - fS.y; if (er > 0.f) { num += fabsf(ef - er); ++cnt; }
        er = rSp - rS.z;  ef = fSp - fS.z;  if (er > 0.f) { num += fabsf(ef - er); ++cnt; }

        fp_ = fc_; fc_ = fn_;
        rp_ = rc_; rc_ = rn_;
    }

    // wave reduce -> block reduce -> ONE plain store per block (no atomics)
    for (int off = 32; off; off >>= 1) {
        num += __shfl_down(num, off);
        cnt += __shfl_down(cnt, off);
    }
    __shared__ float wnum[4];
    __shared__ int   wcnt[4];
    const int wave = t >> 6, lane = t & 63;
    if (lane == 0) { wnum[wave] = num; wcnt[wave] = cnt; }
    __syncthreads();
    if (t == 0) {
        pnum[blockIdx.x] = wnum[0] + wnum[1] + wnum[2] + wnum[3];
        pcnt[blockIdx.x] = (unsigned int)(wcnt[0] + wcnt[1] + wcnt[2] + wcnt[3]);
    }
}

__global__ __launch_bounds__(256) void reduce_kernel(
    const float* __restrict__ pnum, const unsigned int* __restrict__ pcnt,
    float* __restrict__ out)
{
    const int t = threadIdx.x;
    double             n = 0.0;
    unsigned long long c = 0;
    for (int i = t; i < NBLK; i += 256) { n += (double)pnum[i]; c += pcnt[i]; }
    for (int off = 32; off; off >>= 1) {
        n += __shfl_down(n, off);
        c += __shfl_down(c, off);
    }
    __shared__ double             sn[4];
    __shared__ unsigned long long sc[4];
    const int wave = t >> 6, lane = t & 63;
    if (lane == 0) { sn[wave] = n; sc[wave] = c; }
    __syncthreads();
    if (t == 0) {
        const double N = sn[0] + sn[1] + sn[2] + sn[3];
        const double C = (double)(sc[0] + sc[1] + sc[2] + sc[3]);
        out[0] = (float)(N / C / 32.0);
    }
}

extern "C" void kernel_launch(void* const* d_in, const int* in_sizes, int n_in,
                              void* d_out, int out_size, void* d_ws, size_t ws_size,
                              hipStream_t stream)
{
    const float* fake = (const float*)d_in[0];
    const float* real = (const float*)d_in[1];
    float* out = (float*)d_out;

    float*        pnum = (float*)d_ws;                            // 1024 floats
    unsigned int* pcnt = (unsigned int*)((char*)d_ws + NBLK * 4); // 1024 uints

    sobel_loss_kernel<<<NBLK, 256, 0, stream>>>(fake, real, pnum, pcnt);
    reduce_kernel<<<1, 256, 0, stream>>>(pnum, pcnt, out);
}

// Round 11
// 46.305 us; speedup vs baseline: 1.2396x; 1.0525x over previous
//
#include <hip/hip_runtime.h>

#define HH 1024
#define WW 1024
#define NR 64                          // output rows per block (halo = 2/64 = 3.1%)
#define STRIPS (HH / NR)               // 16 strips per image
#define NBLK (32 * STRIPS)             // 512 blocks, 2048 waves (8 waves/CU)

struct Row { float l; float4 v; float r; };

__device__ __forceinline__ Row ldrow(const float* __restrict__ img, int y,
                                     int x0, int xl, int xr) {
    const float* p = img + (size_t)y * WW;
    Row r;
    r.v = *reinterpret_cast<const float4*>(p + x0);
    r.l = p[xl];                        // clamped halo: neighbor's cache line
    r.r = p[xr];
    return r;
}

__global__ __launch_bounds__(256) void sobel_loss_kernel(
    const float* __restrict__ fake, const float* __restrict__ real,
    float* __restrict__ pnum, unsigned int* __restrict__ pcnt)
{
    const int t  = threadIdx.x;
    const int b  = blockIdx.x / STRIPS;
    const int y0 = (blockIdx.x % STRIPS) * NR;
    const float* fimg = fake + (size_t)b * HH * WW;
    const float* rimg = real + (size_t)b * HH * WW;

    const int x0 = 4 * t;
    const int xl = max(x0 - 1, 0);          // clamp -> edge replicate
    const int xr = min(x0 + 4, WW - 1);

    Row fp_ = ldrow(fimg, max(y0 - 1, 0), x0, xl, xr);
    Row fc_ = ldrow(fimg, y0,             x0, xl, xr);
    Row rp_ = ldrow(rimg, max(y0 - 1, 0), x0, xl, xr);
    Row rc_ = ldrow(rimg, y0,             x0, xl, xr);

    float num = 0.f;
    int   cnt = 0;

    #pragma unroll 8
    for (int i = 0; i < NR; ++i) {
        const int yn = min(y0 + i + 1, HH - 1);
        Row fn_ = ldrow(fimg, yn, x0, xl, xr);
        Row rn_ = ldrow(rimg, yn, x0, xl, xr);

        // vertical smooth S = (p + 2c) + n  — exact jax FP order
        const float fSm = fp_.l + 2.f * fc_.l + fn_.l;
        const float rSm = rp_.l + 2.f * rc_.l + rn_.l;
        float4 fS, rS;
        fS.x = fp_.v.x + 2.f * fc_.v.x + fn_.v.x;
        fS.y = fp_.v.y + 2.f * fc_.v.y + fn_.v.y;
        fS.z = fp_.v.z + 2.f * fc_.v.z + fn_.v.z;
        fS.w = fp_.v.w + 2.f * fc_.v.w + fn_.v.w;
        rS.x = rp_.v.x + 2.f * rc_.v.x + rn_.v.x;
        rS.y = rp_.v.y + 2.f * rc_.v.y + rn_.v.y;
        rS.z = rp_.v.z + 2.f * rc_.v.z + rn_.v.z;
        rS.w = rp_.v.w + 2.f * rc_.v.w + rn_.v.w;
        const float fSp = fp_.r + 2.f * fc_.r + fn_.r;
        const float rSp = rp_.r + 2.f * rc_.r + rn_.r;

        float ef, er;
        er = rS.y - rSm;  ef = fS.y - fSm;  if (er > 0.f) { num += fabsf(ef - er); ++cnt; }
        er = rS.z - rS.x; ef = fS.z - fS.x; if (er > 0.f) { num += fabsf(ef - er); ++cnt; }
        er = rS.w - rS.y; ef = fS.w - fS.y; if (er > 0.f) { num += fabsf(ef - er); ++cnt; }
        er = rSp - rS.z;  ef = fSp - fS.z;  if (er > 0.f) { num += fabsf(ef - er); ++cnt; }

        fp_ = fc_; fc_ = fn_;
        rp_ = rc_; rc_ = rn_;
    }

    // wave reduce -> block reduce -> ONE plain store per block (no atomics)
    for (int off = 32; off; off >>= 1) {
        num += __shfl_down(num, off);
        cnt += __shfl_down(cnt, off);
    }
    __shared__ float wnum[4];
    __shared__ int   wcnt[4];
    const int wave = t >> 6, lane = t & 63;
    if (lane == 0) { wnum[wave] = num; wcnt[wave] = cnt; }
    __syncthreads();
    if (t == 0) {
        pnum[blockIdx.x] = wnum[0] + wnum[1] + wnum[2] + wnum[3];
        pcnt[blockIdx.x] = (unsigned int)(wcnt[0] + wcnt[1] + wcnt[2] + wcnt[3]);
    }
}

__global__ __launch_bounds__(256) void reduce_kernel(
    const float* __restrict__ pnum, const unsigned int* __restrict__ pcnt,
    float* __restrict__ out)
{
    const int t = threadIdx.x;
    double             n = 0.0;
    unsigned long long c = 0;
    for (int i = t; i < NBLK; i += 256) { n += (double)pnum[i]; c += pcnt[i]; }
    for (int off = 32; off; off >>= 1) {
        n += __shfl_down(n, off);
        c += __shfl_down(c, off);
    }
    __shared__ double             sn[4];
    __shared__ unsigned long long sc[4];
    const int wave = t >> 6, lane = t & 63;
    if (lane == 0) { sn[wave] = n; sc[wave] = c; }
    __syncthreads();
    if (t == 0) {
        const double N = sn[0] + sn[1] + sn[2] + sn[3];
        const double C = (double)(sc[0] + sc[1] + sc[2] + sc[3]);
        out[0] = (float)(N / C / 32.0);
    }
}

extern "C" void kernel_launch(void* const* d_in, const int* in_sizes, int n_in,
                              void* d_out, int out_size, void* d_ws, size_t ws_size,
                              hipStream_t stream)
{
    const float* fake = (const float*)d_in[0];
    const float* real = (const float*)d_in[1];
    float* out = (float*)d_out;

    float*        pnum = (float*)d_ws;                            // 512 floats
    unsigned int* pcnt = (unsigned int*)((char*)d_ws + NBLK * 4); // 512 uints

    sobel_loss_kernel<<<NBLK, 256, 0, stream>>>(fake, real, pnum, pcnt);
    reduce_kernel<<<1, 256, 0, stream>>>(pnum, pcnt, out);
}